// Round 3
// baseline (745.480 us; speedup 1.0000x reference)
//
#include <hip/hip_runtime.h>
#include <math.h>

// Problem constants (from reference)
#define LL   2048     // seq len
#define BB   64       // batch
#define EE   256      // embedding
#define HH   128      // lstm hidden per dir
#define GG   512      // 4*H gates
#define TT   128      // utterances (L / SEP_EVERY)
#define SEPT 50256

// ---------------------------------------------------------------------------
// Kernel 1: per-column prefix-scan of SEP flags -> seg[t,b], plus per-(utt,b)
// token counts and start offsets (segments are contiguous per column).
// ---------------------------------------------------------------------------
__global__ __launch_bounds__(256) void segscan_k(
    const int* __restrict__ x, int* __restrict__ seg,
    int* __restrict__ cnt, int* __restrict__ start)
{
    int b   = blockIdx.x;    // 0..63
    int tid = threadIdx.x;   // 0..255, 8 tokens each
    __shared__ int tsum[256];
    __shared__ int ucnt[TT];
    __shared__ int ustart[TT];

    int flags[8];
    int local = 0;
#pragma unroll
    for (int i = 0; i < 8; i++) {
        int t = tid * 8 + i;
        flags[i] = (x[t * BB + b] == SEPT) ? 1 : 0;
        local += flags[i];
    }
    tsum[tid] = local;
    __syncthreads();
    int val = local;
    for (int off = 1; off < 256; off <<= 1) {
        int other = (tid >= off) ? tsum[tid - off] : 0;
        __syncthreads();
        val += other;
        tsum[tid] = val;
        __syncthreads();
    }
    int excl = val - local;   // seps strictly before this thread's chunk

    if (tid < TT) ucnt[tid] = 0;
    __syncthreads();
    int run = excl;
#pragma unroll
    for (int i = 0; i < 8; i++) {
        int t = tid * 8 + i;
        int s = run;                 // seg id = #seps before this token
        seg[t * BB + b] = s;
        run += flags[i];
        if (s < TT) atomicAdd(&ucnt[s], 1);
    }
    __syncthreads();
    if (tid == 0) {
        int acc = 0;
        for (int u = 0; u < TT; u++) { ustart[u] = acc; acc += ucnt[u]; }
    }
    __syncthreads();
    if (tid < TT) {
        cnt[tid * BB + b]   = ucnt[tid];
        start[tid * BB + b] = ustart[tid];
    }
}

// ---------------------------------------------------------------------------
// Kernel 2: embedding gather + mean pool. One WAVE per (utt,b); lane holds a
// float4 column slice -> one coalesced 1KB row read per token. Grid = 2048.
// ---------------------------------------------------------------------------
__global__ __launch_bounds__(256) void pool_k(
    const int* __restrict__ x, const float* __restrict__ emb,
    const int* __restrict__ cnt, const int* __restrict__ start,
    float* __restrict__ up)
{
    int wid  = threadIdx.x >> 6;
    int lane = threadIdx.x & 63;
    int bid  = blockIdx.x * 4 + wid;   // u*64+b, bid in [0,8192)
    int b    = bid & 63;
    int c    = cnt[bid];
    int st   = start[bid];

    float4 acc = {0.f, 0.f, 0.f, 0.f};
    int tok = (c > 0) ? x[st * BB + b] : 0;
    for (int j = 0; j < c; j++) {
        int tok_n = (j + 1 < c) ? x[(st + j + 1) * BB + b] : 0;  // prefetch
        float4 v = ((const float4*)(emb + (size_t)tok * EE))[lane];
        acc.x += v.x; acc.y += v.y; acc.z += v.z; acc.w += v.w;
        tok = tok_n;
    }
    float inv = (c > 0) ? 1.f / (float)c : 0.f;
    float4 r = {acc.x * inv, acc.y * inv, acc.z * inv, acc.w * inv};
    ((float4*)(up + (size_t)bid * EE))[lane] = r;
}

// ---------------------------------------------------------------------------
// Kernel 3: xp = u @ W_cat^T + (b_ih + b_hh).  fp32 register-tiled GEMM, v2.
// 128x128 tile, 256 threads, 8x8 micro-tile: 16 FMA per ds_read_b128 (was 8).
// Grid (64, 8) = 512 blocks = 2/CU. Compute floor 27 us at 157 TF.
// ---------------------------------------------------------------------------
__global__ __launch_bounds__(256) void xp_gemm_k(
    const float* __restrict__ A,
    const float* __restrict__ wf, const float* __restrict__ wb,
    const float* __restrict__ bihf, const float* __restrict__ bhhf,
    const float* __restrict__ bihb, const float* __restrict__ bhhb,
    float* __restrict__ C)
{
    __shared__ float As[32][128];   // [k][m] 16 KB
    __shared__ float Bs[32][128];   // [k][n] 16 KB
    int tid  = threadIdx.x;
    int row0 = blockIdx.x * 128;    // 64 blocks
    int col0 = blockIdx.y * 128;    // 8 blocks
    int tx = tid & 15, ty = tid >> 4;   // 16 x 16 threads, 8x8 micro
    float acc[8][8] = {};

    for (int k0 = 0; k0 < EE; k0 += 32) {
#pragma unroll
        for (int i = 0; i < 4; i++) {
            int idx = tid + i * 256;       // float4 slot, 1024 total
            int m   = idx >> 3;            // 0..127
            int k4  = idx & 7;             // 0..7
            float4 av = *(const float4*)(A + (size_t)(row0 + m) * EE + k0 + k4 * 4);
            As[k4 * 4 + 0][m] = av.x; As[k4 * 4 + 1][m] = av.y;
            As[k4 * 4 + 2][m] = av.z; As[k4 * 4 + 3][m] = av.w;
        }
#pragma unroll
        for (int i = 0; i < 4; i++) {
            int idx = tid + i * 256;
            int n   = idx >> 3;
            int k4  = idx & 7;
            int gc  = col0 + n;
            const float* wsrc = (gc < GG) ? (wf + (size_t)gc * EE)
                                          : (wb + (size_t)(gc - GG) * EE);
            float4 bv = *(const float4*)(wsrc + k0 + k4 * 4);
            Bs[k4 * 4 + 0][n] = bv.x; Bs[k4 * 4 + 1][n] = bv.y;
            Bs[k4 * 4 + 2][n] = bv.z; Bs[k4 * 4 + 3][n] = bv.w;
        }
        __syncthreads();
#pragma unroll
        for (int k = 0; k < 32; k++) {
            float a8[8], b8[8];
            *(float4*)&a8[0] = *(const float4*)&As[k][ty * 8 + 0];
            *(float4*)&a8[4] = *(const float4*)&As[k][ty * 8 + 4];
            *(float4*)&b8[0] = *(const float4*)&Bs[k][tx * 8 + 0];
            *(float4*)&b8[4] = *(const float4*)&Bs[k][tx * 8 + 4];
#pragma unroll
            for (int i = 0; i < 8; i++)
#pragma unroll
                for (int j = 0; j < 8; j++)
                    acc[i][j] += a8[i] * b8[j];
        }
        __syncthreads();
    }

    // epilogue: bias + float4 stores
    float bias[8];
#pragma unroll
    for (int j = 0; j < 8; j++) {
        int gc = col0 + tx * 8 + j;
        bias[j] = (gc < GG) ? (bihf[gc] + bhhf[gc])
                            : (bihb[gc - GG] + bhhb[gc - GG]);
    }
#pragma unroll
    for (int i = 0; i < 8; i++) {
        int r = row0 + ty * 8 + i;
        float4 v0 = {acc[i][0] + bias[0], acc[i][1] + bias[1],
                     acc[i][2] + bias[2], acc[i][3] + bias[3]};
        float4 v1 = {acc[i][4] + bias[4], acc[i][5] + bias[5],
                     acc[i][6] + bias[6], acc[i][7] + bias[7]};
        *(float4*)(C + (size_t)r * 1024 + col0 + tx * 8 + 0) = v0;
        *(float4*)(C + (size_t)r * 1024 + col0 + tx * 8 + 4) = v1;
    }
}

// ---------------------------------------------------------------------------
// Fast activations
// ---------------------------------------------------------------------------
__device__ __forceinline__ float sigm_f(float x) {
    return 1.f / (1.f + __expf(-x));
}
__device__ __forceinline__ float tanh_f(float x) {
    return 1.f - 2.f / (__expf(2.f * x) + 1.f);
}

// ---------------------------------------------------------------------------
// Kernel 4: LSTM recurrence — r14: HALF-RESIDENT weights (hedge design).
//
// r12/r13 post-mortem: both occupancy attributes failed to lift the ~128-reg
// allocation cap (VGPR stuck at 84/88); the full 128-float weight set gets
// scratch-spilled, and scratch is L2-backed -> same 256 KB/step stream ->
// 113 us (= measured 37 TB/s L2-fabric ceiling, m56).
//
// r14 design works under EITHER allocator outcome:
//   * 64 floats (16 float4) asm-pinned: total demand ~125 regs stays UNDER
//     the empirical 128 cap -> RA has no pressure reason to spill them.
//   * remaining 64 floats are plain in-loop loads: if the budget is 128 the
//     compiler sinks them (streams 128 KB/step = 1024 cyc, half of today);
//     if waves_per_eu(1,2) does lift the cap it hoists them (full
//     residency). Both outcomes beat 113 us.
// FP summation order per accumulator preserved (k-ascending) -> absmax
// unchanged. Expect step ~1100-1300 cyc -> 60-80 us.
// ---------------------------------------------------------------------------
__global__
__attribute__((amdgpu_flat_work_group_size(512, 512), amdgpu_waves_per_eu(1, 2)))
void lstm_rec_k(
    const float* __restrict__ xp,            // [T*B][1024]
    const float* __restrict__ whh_f, const float* __restrict__ whh_b,
    float* __restrict__ hout)                // [2][T][B][H]
{
    int bid = blockIdx.x;
    int dir = bid >> 6;
    int b   = bid & 63;
    int tid = threadIdx.x;
    int wv  = tid >> 6;      // wave id 0..7 -> k-slice [16wv, 16wv+16)
    int l   = tid & 63;      // lane -> gate set {l + 64j}
    const float* whh = dir ? whh_b : whh_f;

    // Resident half: w[j][k], k in [16wv, 16wv+8), asm-pinned (16 float4).
    float4 wr[16];
    const float* base[8];
#pragma unroll
    for (int j = 0; j < 8; j++) {
        base[j] = whh + (size_t)(l + 64 * j) * HH + 16 * wv;
        asm volatile("global_load_dwordx4 %0, %1, off"
                     : "=v"(wr[j * 2 + 0]) : "v"(base[j]) : "memory");
        asm volatile("global_load_dwordx4 %0, %1, off offset:16"
                     : "=v"(wr[j * 2 + 1]) : "v"(base[j]) : "memory");
    }
    asm volatile("s_waitcnt vmcnt(0)" ::: "memory");
    __builtin_amdgcn_sched_barrier(0);

    __shared__ __align__(16) float h_lds[HH];
    __shared__ float part[GG][9];   // [gate][wave], pad 9 -> 0 conflicts (r2)
    __shared__ float act[GG];

    int g    = tid;                 // gate this thread reduces in phase 2
    int sect = g >> 7;              // 0:i 1:f 2:g 3:o (wave-uniform)

    float c = 0.f;                  // cell state (threads < 128)
    if (g < HH) h_lds[g] = 0.f;
    __syncthreads();

    int t0   = dir ? (TT - 1) : 0;
    float xg = xp[(size_t)(t0 * BB + b) * 1024 + dir * GG + g];

    for (int s = 0; s < TT; s++) {
        // ---- phase 1: partial dots over this wave's k-slice ----
        float hsA[8], hsB[8];
        *(float4*)&hsA[0] = *(const float4*)&h_lds[wv * 16 + 0];
        *(float4*)&hsA[4] = *(const float4*)&h_lds[wv * 16 + 4];
        *(float4*)&hsB[0] = *(const float4*)&h_lds[wv * 16 + 8];
        *(float4*)&hsB[4] = *(const float4*)&h_lds[wv * 16 + 12];

        float acc[8] = {0.f, 0.f, 0.f, 0.f, 0.f, 0.f, 0.f, 0.f};

        // resident half: k = 0..7 of this wave's slice (k-ascending per acc)
#pragma unroll
        for (int j = 0; j < 8; j++) {
            float4 q0 = wr[j * 2 + 0];
            float4 q1 = wr[j * 2 + 1];
            acc[j] += q0.x * hsA[0];
            acc[j] += q0.y * hsA[1];
            acc[j] += q0.z * hsA[2];
            acc[j] += q0.w * hsA[3];
            acc[j] += q1.x * hsA[4];
            acc[j] += q1.y * hsA[5];
            acc[j] += q1.z * hsA[6];
            acc[j] += q1.w * hsA[7];
        }

        // streamed half: k = 8..15 of this wave's slice. Plain loads: the
        // compiler sinks these (streams 128 KB/step from L2) or hoists them
        // (full residency) depending on its register budget — both are wins.
#pragma unroll
        for (int j = 0; j < 8; j++) {
            float4 q0 = *(const float4*)(base[j] + 8);
            float4 q1 = *(const float4*)(base[j] + 12);
            acc[j] += q0.x * hsB[0];
            acc[j] += q0.y * hsB[1];
            acc[j] += q0.z * hsB[2];
            acc[j] += q0.w * hsB[3];
            acc[j] += q1.x * hsB[4];
            acc[j] += q1.y * hsB[5];
            acc[j] += q1.z * hsB[6];
            acc[j] += q1.w * hsB[7];
        }

        // prefetch next step's xp while FMAs drain
        float xg_next = xg;
        if (s < TT - 1) {
            int tn = dir ? (TT - 2 - s) : (s + 1);
            xg_next = xp[(size_t)(tn * BB + b) * 1024 + dir * GG + g];
        }

#pragma unroll
        for (int j = 0; j < 8; j++)
            part[l + 64 * j][wv] = acc[j];
        __syncthreads();

        // ---- phase 2: reduce partials for gate g, activate ----
        float sum = xg;
#pragma unroll
        for (int w2 = 0; w2 < 8; w2++)
            sum += part[g][w2];
        act[g] = (sect == 2) ? tanh_f(sum) : sigm_f(sum);
        __syncthreads();

        // ---- phase 3: c/h update for hidden unit tid (<128) ----
        if (tid < HH) {
            float si = act[tid], sf = act[HH + tid];
            float tg = act[2 * HH + tid], so = act[3 * HH + tid];
            c = sf * c + si * tg;
            float h = so * tanh_f(c);
            h_lds[tid] = h;
            int t = dir ? (TT - 1 - s) : s;
            hout[((size_t)(dir * TT + t) * BB + b) * HH + tid] = h;
        }
        xg = xg_next;
        __syncthreads();   // close r2's h_lds race (phase-3 write vs next phase-1 read)
    }
}

// ---------------------------------------------------------------------------
// Kernel 5: head — logits, softmax, argmax, chosen policy. One wave per row.
// ---------------------------------------------------------------------------
__global__ __launch_bounds__(256) void head_k(
    const float* __restrict__ hbuf,           // [2][T][B][H]
    const float* __restrict__ wout, const float* __restrict__ bout,
    float* __restrict__ out)
{
    int wid  = threadIdx.x >> 6;
    int lane = threadIdx.x & 63;
    int row  = blockIdx.x * 4 + wid;          // t*64+b, 0..8191
    int t = row >> 6, b = row & 63;
    const float* hf = hbuf + ((size_t)(t)      * BB + b) * HH;
    const float* hb = hbuf + ((size_t)(TT + t) * BB + b) * HH;

    float l0 = 0.f, l1 = 0.f, v;
    v = hf[lane];      l0 += v * wout[lane];           l1 += v * wout[256 + lane];
    v = hf[lane + 64]; l0 += v * wout[64 + lane];      l1 += v * wout[320 + lane];
    v = hb[lane];      l0 += v * wout[128 + lane];     l1 += v * wout[384 + lane];
    v = hb[lane + 64]; l0 += v * wout[192 + lane];     l1 += v * wout[448 + lane];
#pragma unroll
    for (int off = 32; off > 0; off >>= 1) {
        l0 += __shfl_down(l0, off);
        l1 += __shfl_down(l1, off);
    }
    if (lane == 0) {
        l0 += bout[0]; l1 += bout[1];
        float m  = fmaxf(l0, l1);
        float e0 = __expf(l0 - m), e1 = __expf(l1 - m);
        float inv = 1.f / (e0 + e1);
        float p0 = e0 * inv, p1 = e1 * inv;
        int amax = (l1 > l0) ? 1 : 0;          // tie -> 0, matches jnp.argmax
        out[(size_t)row * 2 + 0] = l0;
        out[(size_t)row * 2 + 1] = l1;
        out[16384 + (size_t)row * 2 + 0] = p0;
        out[16384 + (size_t)row * 2 + 1] = p1;
        out[32768 + row] = amax ? p1 : p0;
        out[40960 + row] = (float)amax;
    }
}

// ---------------------------------------------------------------------------
// Kernel 6: expand utterance mask to tokens, write masked input as float.
// ---------------------------------------------------------------------------
__global__ __launch_bounds__(256) void mask_k(
    const int* __restrict__ x, const int* __restrict__ seg,
    const float* __restrict__ umask, float* __restrict__ out4)
{
    int idx = blockIdx.x * 256 + threadIdx.x;    // < 131072
    int b = idx & 63;
    int s = seg[idx];
    if (s > TT - 1) s = TT - 1;                  // jnp OOB indexing clamps
    if (s < 0) s = 0;
    float keep = umask[s * BB + b];
    out4[idx] = (keep != 0.f) ? (float)x[idx] : 0.f;
}

// ---------------------------------------------------------------------------
extern "C" void kernel_launch(void* const* d_in, const int* in_sizes, int n_in,
                              void* d_out, int out_size, void* d_ws, size_t ws_size,
                              hipStream_t stream)
{
    const int*   x    = (const int*)  d_in[0];
    const float* emb  = (const float*)d_in[1];
    const float* wihf = (const float*)d_in[2];
    const float* whhf = (const float*)d_in[3];
    const float* bihf = (const float*)d_in[4];
    const float* bhhf = (const float*)d_in[5];
    const float* wihb = (const float*)d_in[6];
    const float* whhb = (const float*)d_in[7];
    const float* bihb = (const float*)d_in[8];
    const float* bhhb = (const float*)d_in[9];
    const float* wout = (const float*)d_in[10];
    const float* bout = (const float*)d_in[11];
    float* out = (float*)d_out;
    char*  ws  = (char*)d_ws;

    // workspace layout (bytes)
    int*   seg   = (int*)  (ws + 0);         // 2048*64*4   = 524288
    int*   cnt   = (int*)  (ws + 524288);    // 128*64*4    = 32768
    int*   start = (int*)  (ws + 557056);    // 32768
    float* up    = (float*)(ws + 589824);    // 128*64*256*4  = 8 MB
    float* xp    = (float*)(ws + 8978432);   // 128*64*1024*4 = 32 MB
    float* hbuf  = (float*)(ws + 42532864);  // 2*128*64*128*4 = 8 MB

    segscan_k<<<64, 256, 0, stream>>>(x, seg, cnt, start);
    pool_k<<<2048, 256, 0, stream>>>(x, emb, cnt, start, up);   // 8192 waves
    xp_gemm_k<<<dim3(64, 8), 256, 0, stream>>>(up, wihf, wihb, bihf, bhhf, bihb, bhhb, xp);
    lstm_rec_k<<<128, 512, 0, stream>>>(xp, whhf, whhb, hbuf);
    head_k<<<2048, 256, 0, stream>>>(hbuf, wout, bout, out);
    mask_k<<<512, 256, 0, stream>>>(x, seg, out + 40960, out + 49152);
}

// Round 4
// 313.931 us; speedup vs baseline: 2.3747x; 2.3747x over previous
//
#include <hip/hip_runtime.h>
#include <math.h>

// Problem constants (from reference)
#define LL   2048     // seq len
#define BB   64       // batch
#define EE   256      // embedding
#define HH   128      // lstm hidden per dir
#define GG   512      // 4*H gates
#define TT   128      // utterances (L / SEP_EVERY)
#define SEPT 50256

// ---------------------------------------------------------------------------
// Kernel 1: per-column prefix-scan of SEP flags -> seg[t,b], plus per-(utt,b)
// token counts and start offsets (segments are contiguous per column).
// ---------------------------------------------------------------------------
__global__ __launch_bounds__(256) void segscan_k(
    const int* __restrict__ x, int* __restrict__ seg,
    int* __restrict__ cnt, int* __restrict__ start)
{
    int b   = blockIdx.x;    // 0..63
    int tid = threadIdx.x;   // 0..255, 8 tokens each
    __shared__ int tsum[256];
    __shared__ int ucnt[TT];
    __shared__ int ustart[TT];

    int flags[8];
    int local = 0;
#pragma unroll
    for (int i = 0; i < 8; i++) {
        int t = tid * 8 + i;
        flags[i] = (x[t * BB + b] == SEPT) ? 1 : 0;
        local += flags[i];
    }
    tsum[tid] = local;
    __syncthreads();
    int val = local;
    for (int off = 1; off < 256; off <<= 1) {
        int other = (tid >= off) ? tsum[tid - off] : 0;
        __syncthreads();
        val += other;
        tsum[tid] = val;
        __syncthreads();
    }
    int excl = val - local;   // seps strictly before this thread's chunk

    if (tid < TT) ucnt[tid] = 0;
    __syncthreads();
    int run = excl;
#pragma unroll
    for (int i = 0; i < 8; i++) {
        int t = tid * 8 + i;
        int s = run;                 // seg id = #seps before this token
        seg[t * BB + b] = s;
        run += flags[i];
        if (s < TT) atomicAdd(&ucnt[s], 1);
    }
    __syncthreads();
    if (tid == 0) {
        int acc = 0;
        for (int u = 0; u < TT; u++) { ustart[u] = acc; acc += ucnt[u]; }
    }
    __syncthreads();
    if (tid < TT) {
        cnt[tid * BB + b]   = ucnt[tid];
        start[tid * BB + b] = ustart[tid];
    }
}

// ---------------------------------------------------------------------------
// Kernel 2: embedding gather + mean pool. One WAVE per (utt,b); lane holds a
// float4 column slice -> one coalesced 1KB row read per token. Grid = 2048.
// ---------------------------------------------------------------------------
__global__ __launch_bounds__(256) void pool_k(
    const int* __restrict__ x, const float* __restrict__ emb,
    const int* __restrict__ cnt, const int* __restrict__ start,
    float* __restrict__ up)
{
    int wid  = threadIdx.x >> 6;
    int lane = threadIdx.x & 63;
    int bid  = blockIdx.x * 4 + wid;   // u*64+b, bid in [0,8192)
    int b    = bid & 63;
    int c    = cnt[bid];
    int st   = start[bid];

    float4 acc = {0.f, 0.f, 0.f, 0.f};
    int tok = (c > 0) ? x[st * BB + b] : 0;
    for (int j = 0; j < c; j++) {
        int tok_n = (j + 1 < c) ? x[(st + j + 1) * BB + b] : 0;  // prefetch
        float4 v = ((const float4*)(emb + (size_t)tok * EE))[lane];
        acc.x += v.x; acc.y += v.y; acc.z += v.z; acc.w += v.w;
        tok = tok_n;
    }
    float inv = (c > 0) ? 1.f / (float)c : 0.f;
    float4 r = {acc.x * inv, acc.y * inv, acc.z * inv, acc.w * inv};
    ((float4*)(up + (size_t)bid * EE))[lane] = r;
}

// ---------------------------------------------------------------------------
// Kernel 3: xp = u @ W_cat^T + (b_ih + b_hh).  fp32 register-tiled GEMM, v2.
// 128x128 tile, 256 threads, 8x8 micro-tile: 16 FMA per ds_read_b128 (was 8).
// Grid (64, 8) = 512 blocks = 2/CU. Compute floor 27 us at 157 TF.
// ---------------------------------------------------------------------------
__global__ __launch_bounds__(256) void xp_gemm_k(
    const float* __restrict__ A,
    const float* __restrict__ wf, const float* __restrict__ wb,
    const float* __restrict__ bihf, const float* __restrict__ bhhf,
    const float* __restrict__ bihb, const float* __restrict__ bhhb,
    float* __restrict__ C)
{
    __shared__ float As[32][128];   // [k][m] 16 KB
    __shared__ float Bs[32][128];   // [k][n] 16 KB
    int tid  = threadIdx.x;
    int row0 = blockIdx.x * 128;    // 64 blocks
    int col0 = blockIdx.y * 128;    // 8 blocks
    int tx = tid & 15, ty = tid >> 4;   // 16 x 16 threads, 8x8 micro
    float acc[8][8] = {};

    for (int k0 = 0; k0 < EE; k0 += 32) {
#pragma unroll
        for (int i = 0; i < 4; i++) {
            int idx = tid + i * 256;       // float4 slot, 1024 total
            int m   = idx >> 3;            // 0..127
            int k4  = idx & 7;             // 0..7
            float4 av = *(const float4*)(A + (size_t)(row0 + m) * EE + k0 + k4 * 4);
            As[k4 * 4 + 0][m] = av.x; As[k4 * 4 + 1][m] = av.y;
            As[k4 * 4 + 2][m] = av.z; As[k4 * 4 + 3][m] = av.w;
        }
#pragma unroll
        for (int i = 0; i < 4; i++) {
            int idx = tid + i * 256;
            int n   = idx >> 3;
            int k4  = idx & 7;
            int gc  = col0 + n;
            const float* wsrc = (gc < GG) ? (wf + (size_t)gc * EE)
                                          : (wb + (size_t)(gc - GG) * EE);
            float4 bv = *(const float4*)(wsrc + k0 + k4 * 4);
            Bs[k4 * 4 + 0][n] = bv.x; Bs[k4 * 4 + 1][n] = bv.y;
            Bs[k4 * 4 + 2][n] = bv.z; Bs[k4 * 4 + 3][n] = bv.w;
        }
        __syncthreads();
#pragma unroll
        for (int k = 0; k < 32; k++) {
            float a8[8], b8[8];
            *(float4*)&a8[0] = *(const float4*)&As[k][ty * 8 + 0];
            *(float4*)&a8[4] = *(const float4*)&As[k][ty * 8 + 4];
            *(float4*)&b8[0] = *(const float4*)&Bs[k][tx * 8 + 0];
            *(float4*)&b8[4] = *(const float4*)&Bs[k][tx * 8 + 4];
#pragma unroll
            for (int i = 0; i < 8; i++)
#pragma unroll
                for (int j = 0; j < 8; j++)
                    acc[i][j] += a8[i] * b8[j];
        }
        __syncthreads();
    }

    // epilogue: bias + float4 stores
    float bias[8];
#pragma unroll
    for (int j = 0; j < 8; j++) {
        int gc = col0 + tx * 8 + j;
        bias[j] = (gc < GG) ? (bihf[gc] + bhhf[gc])
                            : (bihb[gc - GG] + bhhb[gc - GG]);
    }
#pragma unroll
    for (int i = 0; i < 8; i++) {
        int r = row0 + ty * 8 + i;
        float4 v0 = {acc[i][0] + bias[0], acc[i][1] + bias[1],
                     acc[i][2] + bias[2], acc[i][3] + bias[3]};
        float4 v1 = {acc[i][4] + bias[4], acc[i][5] + bias[5],
                     acc[i][6] + bias[6], acc[i][7] + bias[7]};
        *(float4*)(C + (size_t)r * 1024 + col0 + tx * 8 + 0) = v0;
        *(float4*)(C + (size_t)r * 1024 + col0 + tx * 8 + 4) = v1;
    }
}

// ---------------------------------------------------------------------------
// Fast activations
// ---------------------------------------------------------------------------
__device__ __forceinline__ float sigm_f(float x) {
    return 1.f / (1.f + __expf(-x));
}
__device__ __forceinline__ float tanh_f(float x) {
    return 1.f - 2.f / (__expf(2.f * x) + 1.f);
}

// ---------------------------------------------------------------------------
// Kernel 4: LSTM recurrence — r15: RESHAPED for true weight residency.
//
// History: r2-r14 all pinned at 113 us = the 37 TB/s per-CU L2 stream
// ceiling (256 KB weights re-fetched every step). Attempts to make
// 128 floats/thread resident at 512 threads/block failed 3 ways: the RA's
// ~128-VGPR pressure target cannot be lifted (launch_bounds r12,
// waves_per_eu r13) and partial pinning over-subscribed demand (r14,
// 565 us: pinned regs spilled, streamed half serialized).
//
// r15: change the DECOMPOSITION so residency fits UNDER the cap:
//   1024 threads/block, thread = (gate g = tid&511, k-half kap = tid>>9).
//   Weights/thread = 64 floats = 16 float4 = 64 VGPRs; demand ~100 < 128
//   cap -> no pressure -> no spill; asm pin forbids remat-sink. The whole
//   512x128 matrix (65536 fl) is block-register-resident: ZERO per-step
//   weight traffic.
//   Step = p1 (all threads: 64-FMA partial dot; h_lds reads are same-addr
//   wave broadcasts, conflict-free) -> bar -> p2 (tid<128: reduce 2 halves
//   x 4 gates + xg, activate, c/h update, xg prefetch) -> bar.
//   Sum order stays k-ascending (xg + P_half0 + P_half1) -> absmax ~same.
// Predicted: step ~900-1150 cyc -> 48-65 us (from 113).
// ---------------------------------------------------------------------------
__global__ __launch_bounds__(1024) void lstm_rec_k(
    const float* __restrict__ xp,            // [T*B][1024]
    const float* __restrict__ whh_f, const float* __restrict__ whh_b,
    float* __restrict__ hout)                // [2][T][B][H]
{
    int bid = blockIdx.x;
    int dir = bid >> 6;
    int b   = bid & 63;
    int tid = threadIdx.x;       // 0..1023
    int g   = tid & 511;         // gate
    int kap = tid >> 9;          // k-half: 0 -> k[0..63], 1 -> k[64..127]
    const float* whh = dir ? whh_b : whh_f;

    // Resident weights: w[g][64*kap + 0..63] in 16 float4 regs (asm-pinned).
    float4 wr[16];
    {
        const float* wbase = whh + (size_t)g * HH + 64 * kap;
#pragma unroll
        for (int q = 0; q < 16; q++) {
            asm volatile("global_load_dwordx4 %0, %1, off"
                         : "=v"(wr[q]) : "v"(wbase + q * 4) : "memory");
        }
    }
    asm volatile("s_waitcnt vmcnt(0)" ::: "memory");
    __builtin_amdgcn_sched_barrier(0);

    __shared__ __align__(16) float h_lds[HH];
    __shared__ float part[2][GG];   // [k-half][gate], stride-1 -> conflict-free

    float c = 0.f;                  // cell state (threads < 128)
    if (tid < HH) h_lds[tid] = 0.f;
    __syncthreads();

    int t0 = dir ? (TT - 1) : 0;
    float xg4[4];                   // xp gate values for hidden unit tid (<128)
    if (tid < HH) {
        const float* xrow = xp + (size_t)(t0 * BB + b) * 1024 + dir * GG;
        xg4[0] = xrow[tid];
        xg4[1] = xrow[HH + tid];
        xg4[2] = xrow[2 * HH + tid];
        xg4[3] = xrow[3 * HH + tid];
    }

    for (int s = 0; s < TT; s++) {
        // ---- phase 1: 64-FMA partial dot (all 1024 threads) ----
        float pacc = 0.f;
#pragma unroll
        for (int q = 0; q < 16; q++) {
            float4 hv = *(const float4*)&h_lds[64 * kap + q * 4];  // broadcast
            float4 wq = wr[q];
            pacc += wq.x * hv.x;
            pacc += wq.y * hv.y;
            pacc += wq.z * hv.z;
            pacc += wq.w * hv.w;
        }
        part[kap][g] = pacc;
        __syncthreads();

        // ---- phase 2: reduce + activate + c/h update (threads < 128) ----
        if (tid < HH) {
            int i = tid;
            float s_i = xg4[0] + part[0][i]            + part[1][i];
            float s_f = xg4[1] + part[0][HH + i]       + part[1][HH + i];
            float s_g = xg4[2] + part[0][2 * HH + i]   + part[1][2 * HH + i];
            float s_o = xg4[3] + part[0][3 * HH + i]   + part[1][3 * HH + i];
            float si = sigm_f(s_i), sf = sigm_f(s_f);
            float tg = tanh_f(s_g), so = sigm_f(s_o);
            c = sf * c + si * tg;
            float h = so * tanh_f(c);
            h_lds[i] = h;
            int t = dir ? (TT - 1 - s) : s;
            hout[((size_t)(dir * TT + t) * BB + b) * HH + i] = h;

            // prefetch next step's xp gate values (completes during next p1)
            if (s < TT - 1) {
                int tn = dir ? (TT - 2 - s) : (s + 1);
                const float* xrow = xp + (size_t)(tn * BB + b) * 1024 + dir * GG;
                xg4[0] = xrow[i];
                xg4[1] = xrow[HH + i];
                xg4[2] = xrow[2 * HH + i];
                xg4[3] = xrow[3 * HH + i];
            }
        }
        __syncthreads();   // h_lds write (p2) vs next p1 read; part rewrite vs p2 read
    }
}

// ---------------------------------------------------------------------------
// Kernel 5: head — logits, softmax, argmax, chosen policy. One wave per row.
// ---------------------------------------------------------------------------
__global__ __launch_bounds__(256) void head_k(
    const float* __restrict__ hbuf,           // [2][T][B][H]
    const float* __restrict__ wout, const float* __restrict__ bout,
    float* __restrict__ out)
{
    int wid  = threadIdx.x >> 6;
    int lane = threadIdx.x & 63;
    int row  = blockIdx.x * 4 + wid;          // t*64+b, 0..8191
    int t = row >> 6, b = row & 63;
    const float* hf = hbuf + ((size_t)(t)      * BB + b) * HH;
    const float* hb = hbuf + ((size_t)(TT + t) * BB + b) * HH;

    float l0 = 0.f, l1 = 0.f, v;
    v = hf[lane];      l0 += v * wout[lane];           l1 += v * wout[256 + lane];
    v = hf[lane + 64]; l0 += v * wout[64 + lane];      l1 += v * wout[320 + lane];
    v = hb[lane];      l0 += v * wout[128 + lane];     l1 += v * wout[384 + lane];
    v = hb[lane + 64]; l0 += v * wout[192 + lane];     l1 += v * wout[448 + lane];
#pragma unroll
    for (int off = 32; off > 0; off >>= 1) {
        l0 += __shfl_down(l0, off);
        l1 += __shfl_down(l1, off);
    }
    if (lane == 0) {
        l0 += bout[0]; l1 += bout[1];
        float m  = fmaxf(l0, l1);
        float e0 = __expf(l0 - m), e1 = __expf(l1 - m);
        float inv = 1.f / (e0 + e1);
        float p0 = e0 * inv, p1 = e1 * inv;
        int amax = (l1 > l0) ? 1 : 0;          // tie -> 0, matches jnp.argmax
        out[(size_t)row * 2 + 0] = l0;
        out[(size_t)row * 2 + 1] = l1;
        out[16384 + (size_t)row * 2 + 0] = p0;
        out[16384 + (size_t)row * 2 + 1] = p1;
        out[32768 + row] = amax ? p1 : p0;
        out[40960 + row] = (float)amax;
    }
}

// ---------------------------------------------------------------------------
// Kernel 6: expand utterance mask to tokens, write masked input as float.
// ---------------------------------------------------------------------------
__global__ __launch_bounds__(256) void mask_k(
    const int* __restrict__ x, const int* __restrict__ seg,
    const float* __restrict__ umask, float* __restrict__ out4)
{
    int idx = blockIdx.x * 256 + threadIdx.x;    // < 131072
    int b = idx & 63;
    int s = seg[idx];
    if (s > TT - 1) s = TT - 1;                  // jnp OOB indexing clamps
    if (s < 0) s = 0;
    float keep = umask[s * BB + b];
    out4[idx] = (keep != 0.f) ? (float)x[idx] : 0.f;
}

// ---------------------------------------------------------------------------
extern "C" void kernel_launch(void* const* d_in, const int* in_sizes, int n_in,
                              void* d_out, int out_size, void* d_ws, size_t ws_size,
                              hipStream_t stream)
{
    const int*   x    = (const int*)  d_in[0];
    const float* emb  = (const float*)d_in[1];
    const float* wihf = (const float*)d_in[2];
    const float* whhf = (const float*)d_in[3];
    const float* bihf = (const float*)d_in[4];
    const float* bhhf = (const float*)d_in[5];
    const float* wihb = (const float*)d_in[6];
    const float* whhb = (const float*)d_in[7];
    const float* bihb = (const float*)d_in[8];
    const float* bhhb = (const float*)d_in[9];
    const float* wout = (const float*)d_in[10];
    const float* bout = (const float*)d_in[11];
    float* out = (float*)d_out;
    char*  ws  = (char*)d_ws;

    // workspace layout (bytes)
    int*   seg   = (int*)  (ws + 0);         // 2048*64*4   = 524288
    int*   cnt   = (int*)  (ws + 524288);    // 128*64*4    = 32768
    int*   start = (int*)  (ws + 557056);    // 32768
    float* up    = (float*)(ws + 589824);    // 128*64*256*4  = 8 MB
    float* xp    = (float*)(ws + 8978432);   // 128*64*1024*4 = 32 MB
    float* hbuf  = (float*)(ws + 42532864);  // 2*128*64*128*4 = 8 MB

    segscan_k<<<64, 256, 0, stream>>>(x, seg, cnt, start);
    pool_k<<<2048, 256, 0, stream>>>(x, emb, cnt, start, up);   // 8192 waves
    xp_gemm_k<<<dim3(64, 8), 256, 0, stream>>>(up, wihf, wihb, bihf, bhhf, bihb, bhhb, xp);
    lstm_rec_k<<<128, 1024, 0, stream>>>(xp, whhf, whhb, hbuf);
    head_k<<<2048, 256, 0, stream>>>(hbuf, wout, bout, out);
    mask_k<<<512, 256, 0, stream>>>(x, seg, out + 40960, out + 49152);
}

// Round 5
// 301.056 us; speedup vs baseline: 2.4762x; 1.0428x over previous
//
#include <hip/hip_runtime.h>
#include <math.h>

// Problem constants (from reference)
#define LL   2048     // seq len
#define BB   64       // batch
#define EE   256      // embedding
#define HH   128      // lstm hidden per dir
#define GG   512      // 4*H gates
#define TT   128      // utterances (L / SEP_EVERY)
#define SEPT 50256

// ---------------------------------------------------------------------------
// Kernel 1: per-column prefix-scan of SEP flags -> seg[t,b], plus per-(utt,b)
// token counts and start offsets (segments are contiguous per column).
// ---------------------------------------------------------------------------
__global__ __launch_bounds__(256) void segscan_k(
    const int* __restrict__ x, int* __restrict__ seg,
    int* __restrict__ cnt, int* __restrict__ start)
{
    int b   = blockIdx.x;    // 0..63
    int tid = threadIdx.x;   // 0..255, 8 tokens each
    __shared__ int tsum[256];
    __shared__ int ucnt[TT];
    __shared__ int ustart[TT];

    int flags[8];
    int local = 0;
#pragma unroll
    for (int i = 0; i < 8; i++) {
        int t = tid * 8 + i;
        flags[i] = (x[t * BB + b] == SEPT) ? 1 : 0;
        local += flags[i];
    }
    tsum[tid] = local;
    __syncthreads();
    int val = local;
    for (int off = 1; off < 256; off <<= 1) {
        int other = (tid >= off) ? tsum[tid - off] : 0;
        __syncthreads();
        val += other;
        tsum[tid] = val;
        __syncthreads();
    }
    int excl = val - local;   // seps strictly before this thread's chunk

    if (tid < TT) ucnt[tid] = 0;
    __syncthreads();
    int run = excl;
#pragma unroll
    for (int i = 0; i < 8; i++) {
        int t = tid * 8 + i;
        int s = run;                 // seg id = #seps before this token
        seg[t * BB + b] = s;
        run += flags[i];
        if (s < TT) atomicAdd(&ucnt[s], 1);
    }
    __syncthreads();
    if (tid == 0) {
        int acc = 0;
        for (int u = 0; u < TT; u++) { ustart[u] = acc; acc += ucnt[u]; }
    }
    __syncthreads();
    if (tid < TT) {
        cnt[tid * BB + b]   = ucnt[tid];
        start[tid * BB + b] = ustart[tid];
    }
}

// ---------------------------------------------------------------------------
// Kernel 2: embedding gather + mean pool. One WAVE per (utt,b); lane holds a
// float4 column slice -> one coalesced 1KB row read per token. Grid = 2048.
// ---------------------------------------------------------------------------
__global__ __launch_bounds__(256) void pool_k(
    const int* __restrict__ x, const float* __restrict__ emb,
    const int* __restrict__ cnt, const int* __restrict__ start,
    float* __restrict__ up)
{
    int wid  = threadIdx.x >> 6;
    int lane = threadIdx.x & 63;
    int bid  = blockIdx.x * 4 + wid;   // u*64+b, bid in [0,8192)
    int b    = bid & 63;
    int c    = cnt[bid];
    int st   = start[bid];

    float4 acc = {0.f, 0.f, 0.f, 0.f};
    int tok = (c > 0) ? x[st * BB + b] : 0;
    for (int j = 0; j < c; j++) {
        int tok_n = (j + 1 < c) ? x[(st + j + 1) * BB + b] : 0;  // prefetch
        float4 v = ((const float4*)(emb + (size_t)tok * EE))[lane];
        acc.x += v.x; acc.y += v.y; acc.z += v.z; acc.w += v.w;
        tok = tok_n;
    }
    float inv = (c > 0) ? 1.f / (float)c : 0.f;
    float4 r = {acc.x * inv, acc.y * inv, acc.z * inv, acc.w * inv};
    ((float4*)(up + (size_t)bid * EE))[lane] = r;
}

// ---------------------------------------------------------------------------
// Kernel 3: xp = u @ W_cat^T + (b_ih + b_hh).  fp32 register-tiled GEMM, v2.
// 128x128 tile, 256 threads, 8x8 micro-tile: 16 FMA per ds_read_b128 (was 8).
// Grid (64, 8) = 512 blocks = 2/CU. Compute floor 27 us at 157 TF.
// ---------------------------------------------------------------------------
__global__ __launch_bounds__(256) void xp_gemm_k(
    const float* __restrict__ A,
    const float* __restrict__ wf, const float* __restrict__ wb,
    const float* __restrict__ bihf, const float* __restrict__ bhhf,
    const float* __restrict__ bihb, const float* __restrict__ bhhb,
    float* __restrict__ C)
{
    __shared__ float As[32][128];   // [k][m] 16 KB
    __shared__ float Bs[32][128];   // [k][n] 16 KB
    int tid  = threadIdx.x;
    int row0 = blockIdx.x * 128;    // 64 blocks
    int col0 = blockIdx.y * 128;    // 8 blocks
    int tx = tid & 15, ty = tid >> 4;   // 16 x 16 threads, 8x8 micro
    float acc[8][8] = {};

    for (int k0 = 0; k0 < EE; k0 += 32) {
#pragma unroll
        for (int i = 0; i < 4; i++) {
            int idx = tid + i * 256;       // float4 slot, 1024 total
            int m   = idx >> 3;            // 0..127
            int k4  = idx & 7;             // 0..7
            float4 av = *(const float4*)(A + (size_t)(row0 + m) * EE + k0 + k4 * 4);
            As[k4 * 4 + 0][m] = av.x; As[k4 * 4 + 1][m] = av.y;
            As[k4 * 4 + 2][m] = av.z; As[k4 * 4 + 3][m] = av.w;
        }
#pragma unroll
        for (int i = 0; i < 4; i++) {
            int idx = tid + i * 256;
            int n   = idx >> 3;
            int k4  = idx & 7;
            int gc  = col0 + n;
            const float* wsrc = (gc < GG) ? (wf + (size_t)gc * EE)
                                          : (wb + (size_t)(gc - GG) * EE);
            float4 bv = *(const float4*)(wsrc + k0 + k4 * 4);
            Bs[k4 * 4 + 0][n] = bv.x; Bs[k4 * 4 + 1][n] = bv.y;
            Bs[k4 * 4 + 2][n] = bv.z; Bs[k4 * 4 + 3][n] = bv.w;
        }
        __syncthreads();
#pragma unroll
        for (int k = 0; k < 32; k++) {
            float a8[8], b8[8];
            *(float4*)&a8[0] = *(const float4*)&As[k][ty * 8 + 0];
            *(float4*)&a8[4] = *(const float4*)&As[k][ty * 8 + 4];
            *(float4*)&b8[0] = *(const float4*)&Bs[k][tx * 8 + 0];
            *(float4*)&b8[4] = *(const float4*)&Bs[k][tx * 8 + 4];
#pragma unroll
            for (int i = 0; i < 8; i++)
#pragma unroll
                for (int j = 0; j < 8; j++)
                    acc[i][j] += a8[i] * b8[j];
        }
        __syncthreads();
    }

    // epilogue: bias + float4 stores
    float bias[8];
#pragma unroll
    for (int j = 0; j < 8; j++) {
        int gc = col0 + tx * 8 + j;
        bias[j] = (gc < GG) ? (bihf[gc] + bhhf[gc])
                            : (bihb[gc - GG] + bhhb[gc - GG]);
    }
#pragma unroll
    for (int i = 0; i < 8; i++) {
        int r = row0 + ty * 8 + i;
        float4 v0 = {acc[i][0] + bias[0], acc[i][1] + bias[1],
                     acc[i][2] + bias[2], acc[i][3] + bias[3]};
        float4 v1 = {acc[i][4] + bias[4], acc[i][5] + bias[5],
                     acc[i][6] + bias[6], acc[i][7] + bias[7]};
        *(float4*)(C + (size_t)r * 1024 + col0 + tx * 8 + 0) = v0;
        *(float4*)(C + (size_t)r * 1024 + col0 + tx * 8 + 4) = v1;
    }
}

// ---------------------------------------------------------------------------
// Fast activations
// ---------------------------------------------------------------------------
__device__ __forceinline__ float sigm_f(float x) {
    return 1.f / (1.f + __expf(-x));
}
__device__ __forceinline__ float tanh_f(float x) {
    return 1.f - 2.f / (__expf(2.f * x) + 1.f);
}

// ---------------------------------------------------------------------------
// Kernel 4: LSTM recurrence — r16: residency via the DOCUMENTED occupancy
// knob + restored h-reuse.
//
// Ladder of failures r12-r15, distilled: the RA always spills (even asm
// results) down to its occupancy target's VGPR cap. r12/r15 had no
// directive -> default target (2 blocks/CU) capped 128/64. r13/r14's raw
// amdgpu_waves_per_eu attribute didn't move the target. NEVER TRIED:
// __launch_bounds__(block, min_waves_per_EU) — the documented mechanism
// (m97's GEMM holds 164 VGPRs with it).
//
// r16: __launch_bounds__(1024, 4) = exactly 1 block/CU = 128-VGPR cap.
//   Thread = (k-slice kap = wave&7 [16 k], gate-group j = 4*(wave>>3)+0..3):
//   64 weight floats = 64 VGPRs; demand ~100 < 128 -> no pressure, no spill.
//   vs r15: 4 gates/thread restores h-reuse -> 16 FMA per broadcast
//   ds_read_b128, only 64 LDS reads/CU/step (r15 had 256, 4 FMA/read).
//   Phase 2/3 = r2's proven conflict-free part[512][9] reduction; summation
//   order identical to r2 (kap-ascending = k-ascending).
// Predicted: step 2119 -> ~1100-1250 cyc; lstm 113 -> 55-75 us.
// Tell: VGPR_Count ~95-115 = resident; <80 = RA refused again -> pivot.
// ---------------------------------------------------------------------------
__global__ __launch_bounds__(1024, 4) void lstm_rec_k(
    const float* __restrict__ xp,            // [T*B][1024]
    const float* __restrict__ whh_f, const float* __restrict__ whh_b,
    float* __restrict__ hout)                // [2][T][B][H]
{
    int bid = blockIdx.x;
    int dir = bid >> 6;
    int b   = bid & 63;
    int tid = threadIdx.x;       // 0..1023
    int wv  = tid >> 6;          // wave 0..15
    int l   = tid & 63;
    int kap = wv & 7;            // k-slice: k in [16*kap, 16*kap+16)
    int jh  = (wv >> 3) * 4;     // gate-group base: j = jh..jh+3, gate = l+64j
    const float* whh = dir ? whh_b : whh_f;

    // Resident weights: w4[jj*4+q] = whh[(l+64*(jh+jj))*128 + 16*kap + 4q ..]
    float4 w4[16];
#pragma unroll
    for (int jj = 0; jj < 4; jj++) {
        const float* src = whh + (size_t)(l + 64 * (jh + jj)) * HH + 16 * kap;
        asm volatile("global_load_dwordx4 %0, %1, off"
                     : "=v"(w4[jj * 4 + 0]) : "v"(src) : "memory");
        asm volatile("global_load_dwordx4 %0, %1, off offset:16"
                     : "=v"(w4[jj * 4 + 1]) : "v"(src) : "memory");
        asm volatile("global_load_dwordx4 %0, %1, off offset:32"
                     : "=v"(w4[jj * 4 + 2]) : "v"(src) : "memory");
        asm volatile("global_load_dwordx4 %0, %1, off offset:48"
                     : "=v"(w4[jj * 4 + 3]) : "v"(src) : "memory");
    }
    asm volatile("s_waitcnt vmcnt(0)" ::: "memory");
    __builtin_amdgcn_sched_barrier(0);

    __shared__ __align__(16) float h_lds[HH];
    __shared__ float part[GG][9];   // [gate][k-slice], pad 9 -> 0 conflicts (r2)
    __shared__ float act[GG];

    int g    = tid;                 // gate this thread reduces in phase 2 (<512)
    int sect = (g >> 7) & 3;        // 0:i 1:f 2:g 3:o

    float c = 0.f;                  // cell state (threads < 128)
    if (tid < HH) h_lds[tid] = 0.f;
    __syncthreads();

    int t0   = dir ? (TT - 1) : 0;
    float xg = 0.f;
    if (tid < GG)
        xg = xp[(size_t)(t0 * BB + b) * 1024 + dir * GG + g];

    for (int s = 0; s < TT; s++) {
        // ---- phase 1: partial dots, 4 gates x 16 k per thread ----
        float hs[16];
#pragma unroll
        for (int q = 0; q < 4; q++)
            *(float4*)&hs[q * 4] = *(const float4*)&h_lds[16 * kap + q * 4]; // broadcast

        float acc[4] = {0.f, 0.f, 0.f, 0.f};
#pragma unroll
        for (int jj = 0; jj < 4; jj++) {
#pragma unroll
            for (int q = 0; q < 4; q++) {
                float4 wq = w4[jj * 4 + q];
                acc[jj] += wq.x * hs[q * 4 + 0];
                acc[jj] += wq.y * hs[q * 4 + 1];
                acc[jj] += wq.z * hs[q * 4 + 2];
                acc[jj] += wq.w * hs[q * 4 + 3];
            }
        }

        // prefetch next step's xp while FMAs drain (threads < 512)
        float xg_next = xg;
        if (tid < GG && s < TT - 1) {
            int tn = dir ? (TT - 2 - s) : (s + 1);
            xg_next = xp[(size_t)(tn * BB + b) * 1024 + dir * GG + g];
        }

#pragma unroll
        for (int jj = 0; jj < 4; jj++)
            part[l + 64 * (jh + jj)][kap] = acc[jj];
        __syncthreads();

        // ---- phase 2: reduce partials for gate g, activate (threads < 512) ----
        if (tid < GG) {
            float sum = xg;
#pragma unroll
            for (int w2 = 0; w2 < 8; w2++)
                sum += part[g][w2];
            act[g] = (sect == 2) ? tanh_f(sum) : sigm_f(sum);
        }
        __syncthreads();

        // ---- phase 3: c/h update for hidden unit tid (<128) ----
        if (tid < HH) {
            float si = act[tid], sf = act[HH + tid];
            float tg = act[2 * HH + tid], so = act[3 * HH + tid];
            c = sf * c + si * tg;
            float h = so * tanh_f(c);
            h_lds[tid] = h;
            int t = dir ? (TT - 1 - s) : s;
            hout[((size_t)(dir * TT + t) * BB + b) * HH + tid] = h;
        }
        xg = xg_next;
        __syncthreads();   // h_lds write (p3) vs next p1 read; part rewrite vs p2 read
    }
}

// ---------------------------------------------------------------------------
// Kernel 5: head — logits, softmax, argmax, chosen policy. One wave per row.
// ---------------------------------------------------------------------------
__global__ __launch_bounds__(256) void head_k(
    const float* __restrict__ hbuf,           // [2][T][B][H]
    const float* __restrict__ wout, const float* __restrict__ bout,
    float* __restrict__ out)
{
    int wid  = threadIdx.x >> 6;
    int lane = threadIdx.x & 63;
    int row  = blockIdx.x * 4 + wid;          // t*64+b, 0..8191
    int t = row >> 6, b = row & 63;
    const float* hf = hbuf + ((size_t)(t)      * BB + b) * HH;
    const float* hb = hbuf + ((size_t)(TT + t) * BB + b) * HH;

    float l0 = 0.f, l1 = 0.f, v;
    v = hf[lane];      l0 += v * wout[lane];           l1 += v * wout[256 + lane];
    v = hf[lane + 64]; l0 += v * wout[64 + lane];      l1 += v * wout[320 + lane];
    v = hb[lane];      l0 += v * wout[128 + lane];     l1 += v * wout[384 + lane];
    v = hb[lane + 64]; l0 += v * wout[192 + lane];     l1 += v * wout[448 + lane];
#pragma unroll
    for (int off = 32; off > 0; off >>= 1) {
        l0 += __shfl_down(l0, off);
        l1 += __shfl_down(l1, off);
    }
    if (lane == 0) {
        l0 += bout[0]; l1 += bout[1];
        float m  = fmaxf(l0, l1);
        float e0 = __expf(l0 - m), e1 = __expf(l1 - m);
        float inv = 1.f / (e0 + e1);
        float p0 = e0 * inv, p1 = e1 * inv;
        int amax = (l1 > l0) ? 1 : 0;          // tie -> 0, matches jnp.argmax
        out[(size_t)row * 2 + 0] = l0;
        out[(size_t)row * 2 + 1] = l1;
        out[16384 + (size_t)row * 2 + 0] = p0;
        out[16384 + (size_t)row * 2 + 1] = p1;
        out[32768 + row] = amax ? p1 : p0;
        out[40960 + row] = (float)amax;
    }
}

// ---------------------------------------------------------------------------
// Kernel 6: expand utterance mask to tokens, write masked input as float.
// ---------------------------------------------------------------------------
__global__ __launch_bounds__(256) void mask_k(
    const int* __restrict__ x, const int* __restrict__ seg,
    const float* __restrict__ umask, float* __restrict__ out4)
{
    int idx = blockIdx.x * 256 + threadIdx.x;    // < 131072
    int b = idx & 63;
    int s = seg[idx];
    if (s > TT - 1) s = TT - 1;                  // jnp OOB indexing clamps
    if (s < 0) s = 0;
    float keep = umask[s * BB + b];
    out4[idx] = (keep != 0.f) ? (float)x[idx] : 0.f;
}

// ---------------------------------------------------------------------------
extern "C" void kernel_launch(void* const* d_in, const int* in_sizes, int n_in,
                              void* d_out, int out_size, void* d_ws, size_t ws_size,
                              hipStream_t stream)
{
    const int*   x    = (const int*)  d_in[0];
    const float* emb  = (const float*)d_in[1];
    const float* wihf = (const float*)d_in[2];
    const float* whhf = (const float*)d_in[3];
    const float* bihf = (const float*)d_in[4];
    const float* bhhf = (const float*)d_in[5];
    const float* wihb = (const float*)d_in[6];
    const float* whhb = (const float*)d_in[7];
    const float* bihb = (const float*)d_in[8];
    const float* bhhb = (const float*)d_in[9];
    const float* wout = (const float*)d_in[10];
    const float* bout = (const float*)d_in[11];
    float* out = (float*)d_out;
    char*  ws  = (char*)d_ws;

    // workspace layout (bytes)
    int*   seg   = (int*)  (ws + 0);         // 2048*64*4   = 524288
    int*   cnt   = (int*)  (ws + 524288);    // 128*64*4    = 32768
    int*   start = (int*)  (ws + 557056);    // 32768
    float* up    = (float*)(ws + 589824);    // 128*64*256*4  = 8 MB
    float* xp    = (float*)(ws + 8978432);   // 128*64*1024*4 = 32 MB
    float* hbuf  = (float*)(ws + 42532864);  // 2*128*64*128*4 = 8 MB

    segscan_k<<<64, 256, 0, stream>>>(x, seg, cnt, start);
    pool_k<<<2048, 256, 0, stream>>>(x, emb, cnt, start, up);   // 8192 waves
    xp_gemm_k<<<dim3(64, 8), 256, 0, stream>>>(up, wihf, wihb, bihf, bhhf, bihb, bhhb, xp);
    lstm_rec_k<<<128, 1024, 0, stream>>>(xp, whhf, whhb, hbuf);
    head_k<<<2048, 256, 0, stream>>>(hbuf, wout, bout, out);
    mask_k<<<512, 256, 0, stream>>>(x, seg, out + 40960, out + 49152);
}

// Round 6
// 294.805 us; speedup vs baseline: 2.5287x; 1.0212x over previous
//
#include <hip/hip_runtime.h>
#include <hip/hip_fp16.h>
#include <math.h>

// Problem constants (from reference)
#define LL   2048     // seq len
#define BB   64       // batch
#define EE   256      // embedding
#define HH   128      // lstm hidden per dir
#define GG   512      // 4*H gates
#define TT   128      // utterances (L / SEP_EVERY)
#define SEPT 50256

// ---------------------------------------------------------------------------
// Kernel 1: per-column prefix-scan of SEP flags -> seg[t,b], plus per-(utt,b)
// token counts and start offsets (segments are contiguous per column).
// ---------------------------------------------------------------------------
__global__ __launch_bounds__(256) void segscan_k(
    const int* __restrict__ x, int* __restrict__ seg,
    int* __restrict__ cnt, int* __restrict__ start)
{
    int b   = blockIdx.x;    // 0..63
    int tid = threadIdx.x;   // 0..255, 8 tokens each
    __shared__ int tsum[256];
    __shared__ int ucnt[TT];
    __shared__ int ustart[TT];

    int flags[8];
    int local = 0;
#pragma unroll
    for (int i = 0; i < 8; i++) {
        int t = tid * 8 + i;
        flags[i] = (x[t * BB + b] == SEPT) ? 1 : 0;
        local += flags[i];
    }
    tsum[tid] = local;
    __syncthreads();
    int val = local;
    for (int off = 1; off < 256; off <<= 1) {
        int other = (tid >= off) ? tsum[tid - off] : 0;
        __syncthreads();
        val += other;
        tsum[tid] = val;
        __syncthreads();
    }
    int excl = val - local;   // seps strictly before this thread's chunk

    if (tid < TT) ucnt[tid] = 0;
    __syncthreads();
    int run = excl;
#pragma unroll
    for (int i = 0; i < 8; i++) {
        int t = tid * 8 + i;
        int s = run;                 // seg id = #seps before this token
        seg[t * BB + b] = s;
        run += flags[i];
        if (s < TT) atomicAdd(&ucnt[s], 1);
    }
    __syncthreads();
    if (tid == 0) {
        int acc = 0;
        for (int u = 0; u < TT; u++) { ustart[u] = acc; acc += ucnt[u]; }
    }
    __syncthreads();
    if (tid < TT) {
        cnt[tid * BB + b]   = ucnt[tid];
        start[tid * BB + b] = ustart[tid];
    }
}

// ---------------------------------------------------------------------------
// Kernel 2: embedding gather + mean pool. One WAVE per (utt,b); lane holds a
// float4 column slice -> one coalesced 1KB row read per token. Grid = 2048.
// ---------------------------------------------------------------------------
__global__ __launch_bounds__(256) void pool_k(
    const int* __restrict__ x, const float* __restrict__ emb,
    const int* __restrict__ cnt, const int* __restrict__ start,
    float* __restrict__ up)
{
    int wid  = threadIdx.x >> 6;
    int lane = threadIdx.x & 63;
    int bid  = blockIdx.x * 4 + wid;   // u*64+b, bid in [0,8192)
    int b    = bid & 63;
    int c    = cnt[bid];
    int st   = start[bid];

    float4 acc = {0.f, 0.f, 0.f, 0.f};
    int tok = (c > 0) ? x[st * BB + b] : 0;
    for (int j = 0; j < c; j++) {
        int tok_n = (j + 1 < c) ? x[(st + j + 1) * BB + b] : 0;  // prefetch
        float4 v = ((const float4*)(emb + (size_t)tok * EE))[lane];
        acc.x += v.x; acc.y += v.y; acc.z += v.z; acc.w += v.w;
        tok = tok_n;
    }
    float inv = (c > 0) ? 1.f / (float)c : 0.f;
    float4 r = {acc.x * inv, acc.y * inv, acc.z * inv, acc.w * inv};
    ((float4*)(up + (size_t)bid * EE))[lane] = r;
}

// ---------------------------------------------------------------------------
// Kernel 3: xp = u @ W_cat^T + (b_ih + b_hh).  fp32 register-tiled GEMM, v2.
// 128x128 tile, 256 threads, 8x8 micro-tile. Grid (64, 8) = 512 blocks.
// ---------------------------------------------------------------------------
__global__ __launch_bounds__(256) void xp_gemm_k(
    const float* __restrict__ A,
    const float* __restrict__ wf, const float* __restrict__ wb,
    const float* __restrict__ bihf, const float* __restrict__ bhhf,
    const float* __restrict__ bihb, const float* __restrict__ bhhb,
    float* __restrict__ C)
{
    __shared__ float As[32][128];   // [k][m] 16 KB
    __shared__ float Bs[32][128];   // [k][n] 16 KB
    int tid  = threadIdx.x;
    int row0 = blockIdx.x * 128;    // 64 blocks
    int col0 = blockIdx.y * 128;    // 8 blocks
    int tx = tid & 15, ty = tid >> 4;   // 16 x 16 threads, 8x8 micro
    float acc[8][8] = {};

    for (int k0 = 0; k0 < EE; k0 += 32) {
#pragma unroll
        for (int i = 0; i < 4; i++) {
            int idx = tid + i * 256;       // float4 slot, 1024 total
            int m   = idx >> 3;            // 0..127
            int k4  = idx & 7;             // 0..7
            float4 av = *(const float4*)(A + (size_t)(row0 + m) * EE + k0 + k4 * 4);
            As[k4 * 4 + 0][m] = av.x; As[k4 * 4 + 1][m] = av.y;
            As[k4 * 4 + 2][m] = av.z; As[k4 * 4 + 3][m] = av.w;
        }
#pragma unroll
        for (int i = 0; i < 4; i++) {
            int idx = tid + i * 256;
            int n   = idx >> 3;
            int k4  = idx & 7;
            int gc  = col0 + n;
            const float* wsrc = (gc < GG) ? (wf + (size_t)gc * EE)
                                          : (wb + (size_t)(gc - GG) * EE);
            float4 bv = *(const float4*)(wsrc + k0 + k4 * 4);
            Bs[k4 * 4 + 0][n] = bv.x; Bs[k4 * 4 + 1][n] = bv.y;
            Bs[k4 * 4 + 2][n] = bv.z; Bs[k4 * 4 + 3][n] = bv.w;
        }
        __syncthreads();
#pragma unroll
        for (int k = 0; k < 32; k++) {
            float a8[8], b8[8];
            *(float4*)&a8[0] = *(const float4*)&As[k][ty * 8 + 0];
            *(float4*)&a8[4] = *(const float4*)&As[k][ty * 8 + 4];
            *(float4*)&b8[0] = *(const float4*)&Bs[k][tx * 8 + 0];
            *(float4*)&b8[4] = *(const float4*)&Bs[k][tx * 8 + 4];
#pragma unroll
            for (int i = 0; i < 8; i++)
#pragma unroll
                for (int j = 0; j < 8; j++)
                    acc[i][j] += a8[i] * b8[j];
        }
        __syncthreads();
    }

    // epilogue: bias + float4 stores
    float bias[8];
#pragma unroll
    for (int j = 0; j < 8; j++) {
        int gc = col0 + tx * 8 + j;
        bias[j] = (gc < GG) ? (bihf[gc] + bhhf[gc])
                            : (bihb[gc - GG] + bhhb[gc - GG]);
    }
#pragma unroll
    for (int i = 0; i < 8; i++) {
        int r = row0 + ty * 8 + i;
        float4 v0 = {acc[i][0] + bias[0], acc[i][1] + bias[1],
                     acc[i][2] + bias[2], acc[i][3] + bias[3]};
        float4 v1 = {acc[i][4] + bias[4], acc[i][5] + bias[5],
                     acc[i][6] + bias[6], acc[i][7] + bias[7]};
        *(float4*)(C + (size_t)r * 1024 + col0 + tx * 8 + 0) = v0;
        *(float4*)(C + (size_t)r * 1024 + col0 + tx * 8 + 4) = v1;
    }
}

// ---------------------------------------------------------------------------
// Fast activations
// ---------------------------------------------------------------------------
__device__ __forceinline__ float sigm_f(float x) {
    return 1.f / (1.f + __expf(-x));
}
__device__ __forceinline__ float tanh_f(float x) {
    return 1.f - 2.f / (__expf(2.f * x) + 1.f);
}

// ---------------------------------------------------------------------------
// Kernel 3.5: convert W_hh (both dirs) to fp16, PERMUTED for coalesced
// wave-streaming: out[dir][wv][j][lane][k] <- whh[dir][(lane+64j)][16wv+k].
// Each wave in lstm then reads a contiguous 2KB chunk per (wv,j) -> the
// stream is a true 128 KB/step (naive fp16 layout would re-fetch 64B
// sectors for 32B used and lose the whole benefit).
// ---------------------------------------------------------------------------
__global__ __launch_bounds__(256) void cvt_k(
    const float* __restrict__ wf, const float* __restrict__ wb,
    __half* __restrict__ o)
{
    int i = blockIdx.x * 256 + threadIdx.x;   // 0..131071
    int k   = i & 15;
    int l   = (i >> 4) & 63;
    int j   = (i >> 10) & 7;
    int wv  = (i >> 13) & 7;
    int dir = i >> 16;
    const float* src = dir ? wb : wf;
    o[i] = __float2half(src[(l + 64 * j) * HH + 16 * wv + k]);
}

// ---------------------------------------------------------------------------
// Kernel 4: LSTM recurrence — r17: fp16 weight STREAM (r2 structure).
//
// r12-r16 verdict: register residency of the 512x128 fp32 weight tile is
// unreachable from HIP source — the RA scratch-spills even asm-pinned
// VGPRs under 5 different occupancy directives, and scratch is L2-backed
// so dur never moves off the 37 TB/s L2 stream ceiling (113 us). LDS
// staging loses by arithmetic (ds_read_b128 ~85 B/cyc < L2 ~121 B/cyc).
// The remaining lever is BYTES: stream fp16 weights (128 KB/step instead
// of 256) from a pre-permuted copy (cvt_k above), convert in the FMA
// (v_fma_mix / v_cvt). h, xp, c, activations all stay fp32.
// Precision: |w|<=0.088, fp16 rel err <=4.9e-4 -> gate preact err ~2e-4,
// damped by contractive dynamics; expected absmax ~3-8e-4. Known risk:
// an argmax flip near a logit tie would hard-fail -> revert to fp32-r2.
// Predicted: step 2048 -> ~1100-1300 cyc; lstm 113 -> 62-75 us.
// ---------------------------------------------------------------------------
__global__ __launch_bounds__(512, 2) void lstm_rec_k(
    const float* __restrict__ xp,            // [T*B][1024]
    const __half* __restrict__ wh16,         // [2][wv][j][lane][k] permuted
    float* __restrict__ hout)                // [2][T][B][H]
{
    int bid = blockIdx.x;
    int dir = bid >> 6;
    int b   = bid & 63;
    int tid = threadIdx.x;
    int wv  = tid >> 6;      // wave id 0..7 -> k-slice
    int l   = tid & 63;      // lane -> gate set {l + 64j}
    const __half* wh = wh16 + (size_t)dir * (GG * HH);
    // per-gate contiguous 16-half rows: base of (wv, j=0, l)
    const __half* wbase = wh + (((size_t)wv * 8) * 64 + l) * 16;

    __shared__ __align__(16) float h_lds[HH];
    __shared__ float part[GG][9];   // [gate][wave], pad 9 -> 0 conflicts (r2)
    __shared__ float act[GG];

    int g    = tid;                 // gate this thread reduces in phase 2
    int sect = g >> 7;              // 0:i 1:f 2:g 3:o (wave-uniform)

    float c = 0.f;                  // cell state (threads < 128)
    if (g < HH) h_lds[g] = 0.f;
    __syncthreads();

    int t0   = dir ? (TT - 1) : 0;
    float xg = xp[(size_t)(t0 * BB + b) * 1024 + dir * GG + g];

    for (int s = 0; s < TT; s++) {
        // ---- phase 1: partial dots over this wave's k-slice ----
        float hs[16];
#pragma unroll
        for (int k4 = 0; k4 < 4; k4++)
            *(float4*)&hs[k4 * 4] = *(const float4*)&h_lds[wv * 16 + k4 * 4];

        float acc[8] = {0.f, 0.f, 0.f, 0.f, 0.f, 0.f, 0.f, 0.f};
#pragma unroll
        for (int j = 0; j < 8; j++) {
            // 16 halves, contiguous per lane, coalesced 2KB per wave
            float4 q0 = *(const float4*)(wbase + (size_t)j * 1024);      // k 0..7
            float4 q1 = *(const float4*)(wbase + (size_t)j * 1024 + 8);  // k 8..15
            const __half2* ha = (const __half2*)&q0;
            const __half2* hb = (const __half2*)&q1;
#pragma unroll
            for (int p = 0; p < 4; p++) {
                acc[j] = fmaf(__low2float(ha[p]),  hs[2 * p + 0], acc[j]);
                acc[j] = fmaf(__high2float(ha[p]), hs[2 * p + 1], acc[j]);
            }
#pragma unroll
            for (int p = 0; p < 4; p++) {
                acc[j] = fmaf(__low2float(hb[p]),  hs[8 + 2 * p + 0], acc[j]);
                acc[j] = fmaf(__high2float(hb[p]), hs[8 + 2 * p + 1], acc[j]);
            }
        }

        // prefetch next step's xp while FMAs drain
        float xg_next = xg;
        if (s < TT - 1) {
            int tn = dir ? (TT - 2 - s) : (s + 1);
            xg_next = xp[(size_t)(tn * BB + b) * 1024 + dir * GG + g];
        }

#pragma unroll
        for (int j = 0; j < 8; j++)
            part[l + 64 * j][wv] = acc[j];
        __syncthreads();

        // ---- phase 2: reduce partials for gate g, activate ----
        float sum = xg;
#pragma unroll
        for (int w2 = 0; w2 < 8; w2++)
            sum += part[g][w2];
        act[g] = (sect == 2) ? tanh_f(sum) : sigm_f(sum);
        __syncthreads();

        // ---- phase 3: c/h update for hidden unit tid (<128) ----
        if (tid < HH) {
            float si = act[tid], sf = act[HH + tid];
            float tg = act[2 * HH + tid], so = act[3 * HH + tid];
            c = sf * c + si * tg;
            float h = so * tanh_f(c);
            h_lds[tid] = h;
            int t = dir ? (TT - 1 - s) : s;
            hout[((size_t)(dir * TT + t) * BB + b) * HH + tid] = h;
        }
        xg = xg_next;
        __syncthreads();   // close the h_lds race (phase-3 write vs next phase-1 read)
    }
}

// ---------------------------------------------------------------------------
// Kernel 5: head — logits, softmax, argmax, chosen policy. One wave per row.
// ---------------------------------------------------------------------------
__global__ __launch_bounds__(256) void head_k(
    const float* __restrict__ hbuf,           // [2][T][B][H]
    const float* __restrict__ wout, const float* __restrict__ bout,
    float* __restrict__ out)
{
    int wid  = threadIdx.x >> 6;
    int lane = threadIdx.x & 63;
    int row  = blockIdx.x * 4 + wid;          // t*64+b, 0..8191
    int t = row >> 6, b = row & 63;
    const float* hf = hbuf + ((size_t)(t)      * BB + b) * HH;
    const float* hb = hbuf + ((size_t)(TT + t) * BB + b) * HH;

    float l0 = 0.f, l1 = 0.f, v;
    v = hf[lane];      l0 += v * wout[lane];           l1 += v * wout[256 + lane];
    v = hf[lane + 64]; l0 += v * wout[64 + lane];      l1 += v * wout[320 + lane];
    v = hb[lane];      l0 += v * wout[128 + lane];     l1 += v * wout[384 + lane];
    v = hb[lane + 64]; l0 += v * wout[192 + lane];     l1 += v * wout[448 + lane];
#pragma unroll
    for (int off = 32; off > 0; off >>= 1) {
        l0 += __shfl_down(l0, off);
        l1 += __shfl_down(l1, off);
    }
    if (lane == 0) {
        l0 += bout[0]; l1 += bout[1];
        float m  = fmaxf(l0, l1);
        float e0 = __expf(l0 - m), e1 = __expf(l1 - m);
        float inv = 1.f / (e0 + e1);
        float p0 = e0 * inv, p1 = e1 * inv;
        int amax = (l1 > l0) ? 1 : 0;          // tie -> 0, matches jnp.argmax
        out[(size_t)row * 2 + 0] = l0;
        out[(size_t)row * 2 + 1] = l1;
        out[16384 + (size_t)row * 2 + 0] = p0;
        out[16384 + (size_t)row * 2 + 1] = p1;
        out[32768 + row] = amax ? p1 : p0;
        out[40960 + row] = (float)amax;
    }
}

// ---------------------------------------------------------------------------
// Kernel 6: expand utterance mask to tokens, write masked input as float.
// ---------------------------------------------------------------------------
__global__ __launch_bounds__(256) void mask_k(
    const int* __restrict__ x, const int* __restrict__ seg,
    const float* __restrict__ umask, float* __restrict__ out4)
{
    int idx = blockIdx.x * 256 + threadIdx.x;    // < 131072
    int b = idx & 63;
    int s = seg[idx];
    if (s > TT - 1) s = TT - 1;                  // jnp OOB indexing clamps
    if (s < 0) s = 0;
    float keep = umask[s * BB + b];
    out4[idx] = (keep != 0.f) ? (float)x[idx] : 0.f;
}

// ---------------------------------------------------------------------------
extern "C" void kernel_launch(void* const* d_in, const int* in_sizes, int n_in,
                              void* d_out, int out_size, void* d_ws, size_t ws_size,
                              hipStream_t stream)
{
    const int*   x    = (const int*)  d_in[0];
    const float* emb  = (const float*)d_in[1];
    const float* wihf = (const float*)d_in[2];
    const float* whhf = (const float*)d_in[3];
    const float* bihf = (const float*)d_in[4];
    const float* bhhf = (const float*)d_in[5];
    const float* wihb = (const float*)d_in[6];
    const float* whhb = (const float*)d_in[7];
    const float* bihb = (const float*)d_in[8];
    const float* bhhb = (const float*)d_in[9];
    const float* wout = (const float*)d_in[10];
    const float* bout = (const float*)d_in[11];
    float* out = (float*)d_out;
    char*  ws  = (char*)d_ws;

    // workspace layout (bytes)
    int*   seg   = (int*)  (ws + 0);         // 2048*64*4   = 524288
    int*   cnt   = (int*)  (ws + 524288);    // 128*64*4    = 32768
    int*   start = (int*)  (ws + 557056);    // 32768
    float* up    = (float*)(ws + 589824);    // 128*64*256*4  = 8 MB
    float* xp    = (float*)(ws + 8978432);   // 128*64*1024*4 = 32 MB
    float* hbuf  = (float*)(ws + 42532864);  // 2*128*64*128*4 = 8 MB
    // fp16 weight copy lives in the first 256 KB of `up`, which is dead
    // after xp_gemm_k reads it; cvt_k runs between xp_gemm and lstm, and
    // pool_k regenerates up each iteration before xp_gemm. Zero new bytes.
    __half* wh16 = (__half*)up;

    segscan_k<<<64, 256, 0, stream>>>(x, seg, cnt, start);
    pool_k<<<2048, 256, 0, stream>>>(x, emb, cnt, start, up);   // 8192 waves
    xp_gemm_k<<<dim3(64, 8), 256, 0, stream>>>(up, wihf, wihb, bihf, bhhf, bihb, bhhb, xp);
    cvt_k<<<512, 256, 0, stream>>>(whhf, whhb, wh16);
    lstm_rec_k<<<128, 512, 0, stream>>>(xp, wh16, hbuf);
    head_k<<<2048, 256, 0, stream>>>(hbuf, wout, bout, out);
    mask_k<<<512, 256, 0, stream>>>(x, seg, out + 40960, out + 49152);
}